// Round 4
// baseline (222.528 us; speedup 1.0000x reference)
//
#include <hip/hip_runtime.h>
#include <math.h>

static constexpr int BB  = 4;
static constexpr int HH  = 1024;
static constexpr int WW  = 1024;
static constexpr int HWP = HH * WW;       // 1<<20
static constexpr int NPIX = BB * HWP;     // 4<<20
static constexpr int WPR = WW / 64;       // 16 words per image row
static constexpr int PW  = HWP / 64;      // 16384 words per image bitplane
static constexpr int HROUNDS = 3;         // 3 windowed launches cover 12 >= 10 validated rounds
static constexpr int NT  = BB * 8 * 8;    // 256 tiles (128x128 interior, one BLOCK each)
static constexpr int RF  = HROUNDS + 1;   // flags array length
static constexpr int FCN = RF + RF * NT;  // flags[RF] + dirt[RF][NT]

// hysteresis window: 640x640 px = 128x128 interior + 256px halo on each side
static constexpr int WR   = 640;          // window rows
static constexpr int WWD  = 10;           // window words (640/64)
static constexpr int WPAD = 11;           // padded row stride in words (bank-conflict-free)
static constexpr int IR0  = 256;          // interior row offset in window
static constexpr int IW0  = 4;            // interior word offset in window

// fused-stencil tile: 64 wide x 16 tall output (TY=16 -> ~28 KB LDS -> 5 blocks/CU)
static constexpr int TX = 64, TY = 16;
static constexpr int GH = 24,  GW = 72;   // gray   (pre-reflected halo)
static constexpr int HBH = 24, HBW = 68;  // hblur
static constexpr int VBH = 20, VBW = 68;  // vblur
static constexpr int MGH = 18, MGW = 66;  // mag^2

__device__ __forceinline__ int reflect_idx(int i, int n) {
    i = (i < 0) ? -i : i;                 // jnp.pad mode='reflect': -1 -> 1
    return (i >= n) ? (2 * n - 2 - i) : i;
}

// ---------- fused: gray -> hblur -> vblur -> sobel/mag^2 -> dir -> NMS -> ballot ----------
// f64 throughout (validated): f32 blur flips near-tie NMS decisions vs the reference.
__global__ void __launch_bounds__(256) k_front(const float* __restrict__ x,
                                               float* __restrict__ out0,
                                               unsigned long long* __restrict__ weakP,
                                               unsigned long long* __restrict__ strongP,
                                               int* __restrict__ fc,
                                               double w0, double w1, double w2) {
    __shared__ double A[GH * GW];         // gray, then vblur
    __shared__ double B[HBH * HBW];       // hblur, then mag^2
    __shared__ unsigned char P[TY * TX];  // quantized direction, center pixels

    const int tid = threadIdx.x;
    const int x0  = blockIdx.x * TX;
    const int y0  = blockIdx.y * TY;
    const int b   = blockIdx.z;
    const float* base = x + (size_t)b * 3u * HWP;

    if (blockIdx.x == 0 && blockIdx.y == 0 && b == 0) {
        // flags[0]=1, dirt[0][*]=1, rest 0
        for (int i = tid; i < FCN; i += 256)
            fc[i] = (i == 0 || (i >= RF && i < RF + NT)) ? 1 : 0;
    }

    // S1: grayscale into A (rows/cols pre-reflected so later reads are raw)
    for (int idx = tid; idx < GH * GW; idx += 256) {
        int r = idx / GW, c = idx - r * GW;
        int gyr = reflect_idx(y0 + r - 4, HH);
        int gxr = reflect_idx(x0 + c - 4, WW);
        const float* rp = base + (size_t)gyr * WW;
        double rr = (double)rp[gxr];
        double gg = (double)rp[HWP + gxr];
        double bb = (double)rp[2 * HWP + gxr];
        A[idx] = rr * 0.299 + gg * 0.587 + bb * 0.114;
    }
    __syncthreads();

    // S2: hblur into B
    for (int idx = tid; idx < HBH * HBW; idx += 256) {
        int r = idx / HBW, c = idx - r * HBW;
        const double* g = &A[r * GW + c];
        double s;
        s  = w0 * g[0];
        s += w1 * g[1];
        s += w2 * g[2];
        s += w1 * g[3];
        s += w0 * g[4];
        B[idx] = s;
    }
    __syncthreads();

    // S3: vblur into A
    for (int idx = tid; idx < VBH * VBW; idx += 256) {
        int r = idx / VBW, c = idx - r * VBW;
        const double* h = &B[r * HBW + c];
        double s;
        s  = w0 * h[0];
        s += w1 * h[1 * HBW];
        s += w2 * h[2 * HBW];
        s += w1 * h[3 * HBW];
        s += w0 * h[4 * HBW];
        A[idx] = s;
    }
    __syncthreads();

    // S4: SQUARED sobel magnitude into B (0 outside image = NMS zero pad) + dir bytes.
    // All NMS/threshold decisions are monotone in magnitude, so comparing squares is
    // exact; the f64 sqrt is deferred to the <=1024 center pixels that get written.
    for (int idx = tid; idx < MGH * MGW; idx += 256) {
        int r = idx / MGW, c = idx - r * MGW;
        int gy = y0 + r - 1, gx = x0 + c - 1;
        double mg2 = 0.0;
        if (gy >= 0 && gy < HH && gx >= 0 && gx < WW) {
            int ym = gy > 0 ? gy - 1 : 0, yp = gy < HH - 1 ? gy + 1 : HH - 1;
            int xm = gx > 0 ? gx - 1 : 0, xp = gx < WW - 1 ? gx + 1 : WW - 1;
            auto BL = [&](int yy, int xx) -> double {
                return A[(yy - y0 + 2) * VBW + (xx - x0 + 2)];
            };
            double b00 = BL(ym, xm), b01 = BL(ym, gx), b02 = BL(ym, xp);
            double b10 = BL(gy, xm),                   b12 = BL(gy, xp);
            double b20 = BL(yp, xm), b21 = BL(yp, gx), b22 = BL(yp, xp);
            double gxv = -b00 + b02 - 2.0 * b10 + 2.0 * b12 - b20 + b22;
            double gyv = -b00 - 2.0 * b01 - b02 + b20 + 2.0 * b21 + b22;
            mg2 = gxv * gxv + gyv * gyv + 1e-6;
            if (r >= 1 && r < TY + 1 && c >= 1 && c < TX + 1) {
                // octant classification == round(atan2(gy,gx)*4/pi) mod 8, boundary-exact
                double ax = fabs(gxv), ay = fabs(gyv);
                int p;
                if (ay < 0.41421356237309503 * ax)       // tan(22.5deg)
                    p = (gxv >= 0.0) ? 0 : 4;
                else if (ay < 2.4142135623730951 * ax)   // tan(67.5deg)
                    p = (gyv >= 0.0) ? ((gxv >= 0.0) ? 1 : 3)
                                     : ((gxv >= 0.0) ? 7 : 5);
                else
                    p = (gyv >= 0.0) ? 2 : 6;
                P[(r - 1) * TX + (c - 1)] = (unsigned char)p;
            }
        }
        B[r * MGW + c] = mg2;
    }
    __syncthreads();

    // S5: NMS + thresholds + ballot on squared magnitudes (one wave = one 64px row-word)
    for (int k = 0; k < (TX * TY) / 256; ++k) {
        int idx = k * 256 + tid;
        int r = idx >> 6, c = idx & 63;
        double ctr2 = B[(r + 1) * MGW + (c + 1)];
        int p = P[idx];
        int dr = ((425   >> (2 * p)) & 3) - 1;
        int dc = ((36890 >> (2 * p)) & 3) - 1;
        double mp2 = B[(r + 1 + dr) * MGW + (c + 1 + dc)];
        double mn2 = B[(r + 1 - dr) * MGW + (c + 1 - dc)];
        bool ismax = (ctr2 > mp2) && (ctr2 > mn2);      // sqrt is monotone -> same booleans
        out0[(size_t)b * HWP + (size_t)(y0 + r) * WW + (x0 + c)] =
            ismax ? (float)sqrt(ctr2) : 0.0f;
        bool strong = ismax && (ctr2 > 0.04);           // sm > 0.2
        bool weak   = ismax && (ctr2 > 0.01) && !strong;// sm > 0.1
        unsigned long long wb = __ballot(weak);
        unsigned long long sb = __ballot(strong);
        if ((tid & 63) == 0) {
            int word = (y0 + r) * WPR + (x0 >> 6);
            weakP[(size_t)b * PW + word]   = wb;
            strongP[(size_t)b * PW + word] = sb;
        }
    }
}

// ---------------- hysteresis: windowed flood fill, 3 launches total ----------------
__device__ __forceinline__ unsigned long long ks_fill(unsigned long long g, unsigned long long p) {
    unsigned long long q;
    q = p;        g |= q & (g << 1);
    q &= q << 1;  g |= q & (g << 2);
    q &= q << 2;  g |= q & (g << 4);
    q &= q << 4;  g |= q & (g << 8);
    q &= q << 8;  g |= q & (g << 16);
    q &= q << 16; g |= q & (g << 32);
    q = p;        g |= q & (g >> 1);
    q &= q >> 1;  g |= q & (g >> 2);
    q &= q >> 2;  g |= q & (g >> 4);
    q &= q >> 4;  g |= q & (g >> 8);
    q &= q >> 8;  g |= q & (g >> 16);
    q &= q >> 16; g |= q & (g >> 32);
    return g;
}

// 256 blocks x 256 threads; block = 128x128 interior, 640x640 LDS window (256px halo).
// Window closure with zero boundary covers 4 rounds of the validated 64-tile scheme per
// launch (paths for R rounds stay within (R-1)*64+63 px of the target's 64-tile; 256px
// halo => R=4). 3 launches >= 12 rounds >= the 10 validated => exact fixed point
// (monotone closure cannot overshoot). Influence radius 256px = 2 tiles => dirty check
// scans the 5x5 ring. Final launch writes out1 (fused k_edges).
__global__ void __launch_bounds__(256) k_win(const unsigned long long* __restrict__ weakP,
                                             unsigned long long* __restrict__ strongP,
                                             int* __restrict__ flags,
                                             int* __restrict__ dirt,
                                             float* __restrict__ out1, int rr) {
    __shared__ unsigned long long Sw[WR][WPAD];   // strong window (pad col unused)
    __shared__ unsigned long long Wd[WR][WPAD];   // weak window
    __shared__ int chf[4];
    __shared__ int blkch;

    const int tid  = threadIdx.x;
    const int lane = tid & 63;
    const int w    = tid >> 6;            // wave in block 0..3
    const int tile = blockIdx.x;          // 0..255
    const int b  = tile >> 6;
    const int ty = (tile >> 3) & 7;
    const int tx = tile & 7;
    const int tb = b << 6;

    const bool active = (flags[rr - 1] != 0);
    if (!active && rr != HROUNDS) return; // globally quiet; nothing until final write

    int go = 0;
    if (active) {                         // 5x5 dirty ring (influence radius = 2 tiles)
        const int* d0 = dirt + (size_t)(rr - 1) * NT;
        for (int dy = -2; dy <= 2; ++dy) {
            int yy = ty + dy;
            if (yy < 0 || yy > 7) continue;
            for (int dx = -2; dx <= 2; ++dx) {
                int xx = tx + dx;
                if (xx < 0 || xx > 7 || (dy == 0 && dx == 0)) continue;
                go |= d0[tb + (yy << 3) + xx];
            }
        }
    }

    unsigned long long* spl = strongP + (size_t)b * PW;
    const int lr = tid >> 1, lw = tid & 1;            // this thread's interior slot
    const int girow = (ty << 7) + lr;                 // image row of interior slot
    const int giwrd = (tx << 1) + lw;                 // image word of interior slot

    if (go) {                                         // block-uniform
        const unsigned long long* wp = weakP + (size_t)b * PW;
        const int y0w = (ty << 7) - 256;              // window top image row
        const int x0w = (tx << 1) - IW0;              // window left image word

        // load 640x10 window (zeros outside image = conv zero-pad semantics)
        for (int i = tid; i < WR * WWD; i += 256) {
            int r = i / WWD, cw = i - r * WWD;
            int gy = y0w + r, gw = x0w + cw;
            bool in = (gy >= 0) && (gy < HH) && (gw >= 0) && (gw < WPR);
            size_t gi = (size_t)gy * WPR + gw;
            Sw[r][cw] = in ? spl[gi] : 0ull;
            Wd[r][cw] = in ? wp[gi] : 0ull;
        }
        __syncthreads();
        const unsigned long long orig = Sw[IR0 + lr][IW0 + lw];

        // block fixed point: waves sweep 25 subtiles each (Gauss-Seidel, monotone-safe)
        for (;;) {
            if (lane == 0) chf[w] = 0;
            __syncthreads();
            int mych = 0;
            for (int ss = 0; ss < 25; ++ss) {
                int sub = w * 25 + ss;
                int sy = sub / 10, sx = sub - sy * 10;
                int r = (sy << 6) + lane;
                unsigned long long s0 = Sw[r][sx];
                unsigned long long wv = Wd[r][sx];
                unsigned long long ho = 0;
                if (sx > 0) ho |= Sw[r][sx - 1] >> 63;
                if (sx < 9) ho |= Sw[r][sx + 1] << 63;
                unsigned long long top = 0, bot = 0;
                if (lane == 0 && sy > 0) {
                    int ra = r - 1;
                    unsigned long long hs = Sw[ra][sx];
                    top = (hs << 1) | hs | (hs >> 1);
                    if (sx > 0) top |= Sw[ra][sx - 1] >> 63;
                    if (sx < 9) top |= Sw[ra][sx + 1] << 63;
                }
                if (lane == 63 && sy < 9) {
                    int ra = r + 1;
                    unsigned long long hs = Sw[ra][sx];
                    bot = (hs << 1) | hs | (hs >> 1);
                    if (sx > 0) bot |= Sw[ra][sx - 1] >> 63;
                    if (sx < 9) bot |= Sw[ra][sx + 1] << 63;
                }
                // wave-local fixed point: shuffles vertical, ks_fill horizontal
                unsigned long long s = s0;
                for (;;) {
                    unsigned long long sp = (s << 1) | s | (s >> 1) | ho;
                    unsigned long long up = __shfl_up(sp, 1);
                    unsigned long long dn = __shfl_down(sp, 1);
                    if (lane == 0)  up = top;
                    if (lane == 63) dn = bot;
                    unsigned long long g = s | (wv & (up | sp | dn));
                    g = ks_fill(g, wv);
                    int ch = (g != s);
                    s = g;
                    if (!__any(ch)) break;
                }
                if (s != s0) Sw[r][sx] = s;
                mych |= (s != s0);
            }
            if (__any(mych)) { if (lane == 0) chf[w] = 1; }
            __syncthreads();
            int any = chf[0] | chf[1] | chf[2] | chf[3];
            __syncthreads();
            if (!any) break;
        }

        // write back interior (one word per thread); dirt iff interior changed
        unsigned long long nv = Sw[IR0 + lr][IW0 + lw];
        int mydiff = (nv != orig);
        if (tid == 0) blkch = 0;
        __syncthreads();
        if (mydiff) {
            blkch = 1;                                 // benign LDS race
            spl[(size_t)girow * WPR + giwrd] = nv;
        }
        __syncthreads();
        if (tid == 0 && blkch) {
            dirt[(size_t)rr * NT + tb + (ty << 3) + tx] = 1;
            atomicOr(&flags[rr], 1);
        }
    }

    // fused k_edges on the final launch: write this block's 128x128 tile as floats.
    if (rr == HROUNDS) {
        if (!go)                                       // window not loaded; fetch interior
            Sw[IR0 + lr][IW0 + lw] = spl[(size_t)girow * WPR + giwrd];
        __syncthreads();
        float* o = out1 + (size_t)b * HWP;
        for (int it = 0; it < 16; ++it) {
            int fi = (it << 8) + tid;                  // float4 index in tile: 0..4095
            int r  = fi >> 5;                          // 0..127
            int c4 = fi & 31;                          // float4 column 0..31
            unsigned long long bits = Sw[IR0 + r][IW0 + (c4 >> 4)];
            int sh = (c4 & 15) << 2;
            float4 v;
            v.x = ((bits >> (sh + 0)) & 1ull) ? 1.0f : 0.0f;
            v.y = ((bits >> (sh + 1)) & 1ull) ? 1.0f : 0.0f;
            v.z = ((bits >> (sh + 2)) & 1ull) ? 1.0f : 0.0f;
            v.w = ((bits >> (sh + 3)) & 1ull) ? 1.0f : 0.0f;
            int grow = (ty << 7) + r;
            int gcol = (tx << 7) + (c4 << 2);
            *reinterpret_cast<float4*>(&o[(size_t)grow * WW + gcol]) = v;
        }
    }
}

extern "C" void kernel_launch(void* const* d_in, const int* in_sizes, int n_in,
                              void* d_out, int out_size, void* d_ws, size_t ws_size,
                              hipStream_t stream) {
    const float* x = (const float*)d_in[0];
    float* out0 = (float*)d_out;          // suppressed magnitude [4,1,1024,1024]
    float* out1 = out0 + NPIX;            // edges [4,1,1024,1024]

    // workspace: weakP | strongP | fc (flags[RF] + dirt[RF][NT])
    unsigned long long* weakP   = (unsigned long long*)d_ws;
    unsigned long long* strongP = weakP + (size_t)BB * PW;
    int* fc    = (int*)(strongP + (size_t)BB * PW);
    int* flags = fc;
    int* dirt  = fc + RF;

    // gaussian weights, f64 ops mirroring the reference
    double g0 = exp(-2.0), g1 = exp(-0.5), g2 = 1.0;
    double sum = (((g0 + g1) + g2) + g1) + g0;
    double w0 = g0 / sum, w1 = g1 / sum, w2 = g2 / sum;

    k_front<<<dim3(WW / TX, HH / TY, BB), dim3(256), 0, stream>>>(
        x, out0, weakP, strongP, fc, w0, w1, w2);

    for (int r = 1; r <= HROUNDS; ++r)
        k_win<<<dim3(NT), dim3(256), 0, stream>>>(weakP, strongP, flags, dirt, out1, r);
}